// Round 1
// baseline (1261.971 us; speedup 1.0000x reference)
//
#include <hip/hip_runtime.h>
#include <hip/hip_bf16.h>
#include <cstdint>

// MoE top-2: B=4 S=2048 D=1024 F=4096 E=8, all fp32 in/out.
// Sparse grouped-GEMM implementation, bf16 MFMA compute, f32 accumulate.
//
// ws layout (bytes):            requires ws_size >= ~144 MB
//   [0,64)        cnt[8]        tokens routed per expert (zeroed each call)
//   [64,256)      hoff[9]       padded (128-multiple) row prefix offsets
//   [256,65792)   psum[2048][8] per-block softmax-prob partial sums (KL)
//   [65792,..)    list[8][8192] token ids per expert
//   [327936,..)   coef[8][8192] combine weight per routed token
//   [1MB, ~144MB) h bf16        silu(x@W1) activations, padded rows

#define N_TOK 8192
#define D_DIM 1024
#define F_DIM 4096
#define N_EXP 8

#define CNT_OFF   0u
#define HOFF_OFF  64u
#define PSUM_OFF  256u
#define LIST_OFF  65792u
#define COEF_OFF  327936u
#define H_OFF     1048576u

typedef __attribute__((ext_vector_type(8))) short short8;
typedef __attribute__((ext_vector_type(4))) float f32x4;
typedef __attribute__((ext_vector_type(4))) float float4v;
typedef __attribute__((ext_vector_type(2))) unsigned int u32x2;

__device__ __forceinline__ unsigned short f2bf(float x) {
  // round-to-nearest-even f32 -> bf16
  unsigned int u = __float_as_uint(x);
  unsigned int r = (u + 0x7fffu + ((u >> 16) & 1u)) >> 16;
  return (unsigned short)r;
}

// ---------------------------------------------------------------- router ----
__global__ void router_kernel(const float* __restrict__ x,
                              const float* __restrict__ gw,
                              int* __restrict__ cnt, int* __restrict__ list,
                              float* __restrict__ coef,
                              float* __restrict__ psum) {
  const int wave = threadIdx.x >> 6;
  const int lane = threadIdx.x & 63;
  const int t = blockIdx.x * 4 + wave;

  __shared__ float bps[N_EXP];
  if (threadIdx.x < N_EXP) bps[threadIdx.x] = 0.f;
  __syncthreads();

  float lg[8] = {0.f, 0.f, 0.f, 0.f, 0.f, 0.f, 0.f, 0.f};
  const float* xr = x + (size_t)t * D_DIM;
#pragma unroll
  for (int i = 0; i < 16; ++i) {
    int d = lane + i * 64;
    float xv = xr[d];
    float4v w0 = *(const float4v*)(gw + d * 8);
    float4v w1 = *(const float4v*)(gw + d * 8 + 4);
    lg[0] = fmaf(xv, w0.x, lg[0]); lg[1] = fmaf(xv, w0.y, lg[1]);
    lg[2] = fmaf(xv, w0.z, lg[2]); lg[3] = fmaf(xv, w0.w, lg[3]);
    lg[4] = fmaf(xv, w1.x, lg[4]); lg[5] = fmaf(xv, w1.y, lg[5]);
    lg[6] = fmaf(xv, w1.z, lg[6]); lg[7] = fmaf(xv, w1.w, lg[7]);
  }
#pragma unroll
  for (int m = 32; m; m >>= 1) {
#pragma unroll
    for (int e = 0; e < 8; ++e) lg[e] += __shfl_xor(lg[e], m);
  }

  if (lane == 0) {
    // full softmax over experts (for the KL term)
    float mx = lg[0];
#pragma unroll
    for (int e = 1; e < 8; ++e) mx = fmaxf(mx, lg[e]);
    float p[8], s = 0.f;
#pragma unroll
    for (int e = 0; e < 8; ++e) { p[e] = expf(lg[e] - mx); s += p[e]; }
    float inv = 1.f / s;
#pragma unroll
    for (int e = 0; e < 8; ++e) atomicAdd(&bps[e], p[e] * inv);

    // top-2 (first index wins ties, matching lax.top_k)
    int i0 = 0;
#pragma unroll
    for (int e = 1; e < 8; ++e) if (lg[e] > lg[i0]) i0 = e;
    int i1 = (i0 == 0) ? 1 : 0;
#pragma unroll
    for (int e = 0; e < 8; ++e) if (e != i1 && e != i0 && lg[e] > lg[i1]) i1 = e;
    float p0 = 1.f / (1.f + expf(lg[i1] - lg[i0]));
    float p1 = 1.f - p0;
    int s0 = atomicAdd(&cnt[i0], 1);
    list[i0 * N_TOK + s0] = t; coef[i0 * N_TOK + s0] = p0;
    int s1 = atomicAdd(&cnt[i1], 1);
    list[i1 * N_TOK + s1] = t; coef[i1 * N_TOK + s1] = p1;
  }
  __syncthreads();
  if (threadIdx.x < 8) psum[blockIdx.x * 8 + threadIdx.x] = bps[threadIdx.x];
}

// ---------------------------------------------------------------- prefix ----
__global__ void prefix_kernel(const int* __restrict__ cnt, int* __restrict__ hoff) {
  if (threadIdx.x == 0) {
    int o = 0;
#pragma unroll
    for (int e = 0; e < 8; ++e) {
      hoff[e] = o;
      o += ((cnt[e] + 127) >> 7) << 7;
    }
    hoff[8] = o;
  }
}

// -------------------------------------------------------------------- KL ----
__global__ void kl_kernel(const float* __restrict__ psum, float* __restrict__ out_kl) {
  __shared__ float s[8];
  if (threadIdx.x < 8) s[threadIdx.x] = 0.f;
  __syncthreads();
  float loc[8] = {0.f, 0.f, 0.f, 0.f, 0.f, 0.f, 0.f, 0.f};
  for (int r = threadIdx.x; r < 2048; r += 256) {
#pragma unroll
    for (int e = 0; e < 8; ++e) loc[e] += psum[r * 8 + e];
  }
#pragma unroll
  for (int e = 0; e < 8; ++e) atomicAdd(&s[e], loc[e]);
  __syncthreads();
  if (threadIdx.x == 0) {
    float kl = 0.f;
#pragma unroll
    for (int e = 0; e < 8; ++e) {
      float mean = s[e] / 8192.f;
      kl += (logf(0.125f) - logf(mean));
    }
    out_kl[0] = kl * (0.125f * 0.125f);
  }
}

// ------------------------------------------------------- MFMA frag loader ---
// LDS tiles are [rows][64 bf16] (128 B rows), XOR-swizzled: byte ^= (row&7)<<4.
__device__ __forceinline__ short8 ld_frag(const unsigned short* base, int row_base,
                                          int k_base, int lane) {
  int row = row_base + (lane & 15);
  int byte = (row * 128 + (k_base + ((lane >> 4) << 3)) * 2) ^ ((row & 7) << 4);
  return *(const short8*)((const char*)base + byte);
}

// ----------------------------------------------------------------- GEMM1 ----
// h[rows,4096] = silu( X_gather[rows,1024] @ W1[e][1024,4096] ), bf16 out.
__global__ __launch_bounds__(256) void gemm1_kernel(
    const float* __restrict__ x, const float* __restrict__ w1,
    const int* __restrict__ cnt, const int* __restrict__ hoff,
    const int* __restrict__ list, unsigned short* __restrict__ h) {
  const int e = blockIdx.z, mblk = blockIdx.y, nblk = blockIdx.x;
  const int c = cnt[e];
  if (mblk * 128 >= c) return;
  const int tid = threadIdx.x, lane = tid & 63, wave = tid >> 6;
  const int wm = (wave >> 1) * 64, wn = (wave & 1) * 64;

  __shared__ unsigned short At[128 * 64];
  __shared__ unsigned short Bt[128 * 64];
  __shared__ int toks[128];
  if (tid < 128) {
    int slot = mblk * 128 + tid;
    toks[tid] = (slot < c) ? list[e * N_TOK + slot] : -1;
  }
  __syncthreads();

  f32x4 acc[4][4];
#pragma unroll
  for (int i = 0; i < 4; ++i)
#pragma unroll
    for (int j = 0; j < 4; ++j) acc[i][j] = f32x4{0.f, 0.f, 0.f, 0.f};

  const float* w1e = w1 + (size_t)e * D_DIM * F_DIM;
  for (int kc = 0; kc < 16; ++kc) {
    __syncthreads();
    // A: gathered token rows, f32 -> bf16, swizzled [128][64]
#pragma unroll
    for (int it = 0; it < 8; ++it) {
      int lin = it * 256 + tid;
      int row = lin >> 4, c4 = lin & 15;
      int tok = toks[row];
      unsigned int lo = 0u, hi = 0u;
      if (tok >= 0) {
        float4v f = *(const float4v*)(x + (size_t)tok * D_DIM + kc * 64 + c4 * 4);
        lo = (unsigned int)f2bf(f.x) | ((unsigned int)f2bf(f.y) << 16);
        hi = (unsigned int)f2bf(f.z) | ((unsigned int)f2bf(f.w) << 16);
      }
      int byte = (row * 128 + c4 * 8) ^ ((row & 7) << 4);
      *(u32x2*)((char*)At + byte) = u32x2{lo, hi};
    }
    // B: W1T [f 128][d 64] transpose-stage (coalesced f-reads, packed b32 writes)
#pragma unroll
    for (int it = 0; it < 16; ++it) {
      int lin = it * 256 + tid;
      int f_loc = lin & 127, dp = lin >> 7;
      int d = kc * 64 + dp * 2;
      const float* src = w1e + (size_t)d * F_DIM + nblk * 128 + f_loc;
      unsigned int pk = (unsigned int)f2bf(src[0]) |
                        ((unsigned int)f2bf(src[F_DIM]) << 16);
      int byte = (f_loc * 128 + dp * 4) ^ ((f_loc & 7) << 4);
      *(unsigned int*)((char*)Bt + byte) = pk;
    }
    __syncthreads();
#pragma unroll
    for (int ks = 0; ks < 2; ++ks) {
      short8 af[4], bb[4];
#pragma unroll
      for (int mf = 0; mf < 4; ++mf) af[mf] = ld_frag(At, wm + mf * 16, ks * 32, lane);
#pragma unroll
      for (int nf = 0; nf < 4; ++nf) bb[nf] = ld_frag(Bt, wn + nf * 16, ks * 32, lane);
#pragma unroll
      for (int mf = 0; mf < 4; ++mf)
#pragma unroll
        for (int nf = 0; nf < 4; ++nf)
          acc[mf][nf] = __builtin_amdgcn_mfma_f32_16x16x32_bf16(
              af[mf], bb[nf], acc[mf][nf], 0, 0, 0);
    }
  }

  const int hbase = hoff[e] + mblk * 128;
#pragma unroll
  for (int mf = 0; mf < 4; ++mf)
#pragma unroll
    for (int nf = 0; nf < 4; ++nf)
#pragma unroll
      for (int r = 0; r < 4; ++r) {
        float v = acc[mf][nf][r];
        v = v / (1.f + __expf(-v));  // silu
        int row = wm + mf * 16 + ((lane >> 4) << 2) + r;
        int col = nblk * 128 + wn + nf * 16 + (lane & 15);
        h[(size_t)(hbase + row) * F_DIM + col] = f2bf(v);
      }
}

// ----------------------------------------------------------------- GEMM2 ----
// out[tok,:] += coef * ( h[rows,4096] @ W2[e][4096,1024] )
__global__ __launch_bounds__(256) void gemm2_kernel(
    const unsigned short* __restrict__ h, const float* __restrict__ w2,
    const int* __restrict__ cnt, const int* __restrict__ hoff,
    const int* __restrict__ list, const float* __restrict__ coef,
    float* __restrict__ out) {
  const int e = blockIdx.z, mblk = blockIdx.y, nblk = blockIdx.x;
  const int c = cnt[e];
  if (mblk * 128 >= c) return;
  const int tid = threadIdx.x, lane = tid & 63, wave = tid >> 6;
  const int wm = (wave >> 1) * 64, wn = (wave & 1) * 64;

  __shared__ unsigned short At[128 * 64];
  __shared__ unsigned short Bt[128 * 64];

  f32x4 acc[4][4];
#pragma unroll
  for (int i = 0; i < 4; ++i)
#pragma unroll
    for (int j = 0; j < 4; ++j) acc[i][j] = f32x4{0.f, 0.f, 0.f, 0.f};

  const int hbase = hoff[e] + mblk * 128;
  const float* w2e = w2 + (size_t)e * F_DIM * D_DIM;
  for (int kc = 0; kc < 64; ++kc) {
    __syncthreads();
    // A: h rows (already bf16, packed), swizzled [128][64]
#pragma unroll
    for (int it = 0; it < 8; ++it) {
      int lin = it * 256 + tid;
      int row = lin >> 4, c4 = lin & 15;
      u32x2 v = *(const u32x2*)(h + (size_t)(hbase + row) * F_DIM + kc * 64 + c4 * 4);
      int byte = (row * 128 + c4 * 8) ^ ((row & 7) << 4);
      *(u32x2*)((char*)At + byte) = v;
    }
    // B: W2T [dcol 128][k 64] transpose-stage
#pragma unroll
    for (int it = 0; it < 16; ++it) {
      int lin = it * 256 + tid;
      int dcol = lin & 127, kp = lin >> 7;
      int k = kc * 64 + kp * 2;
      const float* src = w2e + (size_t)k * D_DIM + nblk * 128 + dcol;
      unsigned int pk = (unsigned int)f2bf(src[0]) |
                        ((unsigned int)f2bf(src[D_DIM]) << 16);
      int byte = (dcol * 128 + kp * 4) ^ ((dcol & 7) << 4);
      *(unsigned int*)((char*)Bt + byte) = pk;
    }
    __syncthreads();
#pragma unroll
    for (int ks = 0; ks < 2; ++ks) {
      short8 af[4], bb[4];
#pragma unroll
      for (int mf = 0; mf < 4; ++mf) af[mf] = ld_frag(At, wm + mf * 16, ks * 32, lane);
#pragma unroll
      for (int nf = 0; nf < 4; ++nf) bb[nf] = ld_frag(Bt, wn + nf * 16, ks * 32, lane);
#pragma unroll
      for (int mf = 0; mf < 4; ++mf)
#pragma unroll
        for (int nf = 0; nf < 4; ++nf)
          acc[mf][nf] = __builtin_amdgcn_mfma_f32_16x16x32_bf16(
              af[mf], bb[nf], acc[mf][nf], 0, 0, 0);
    }
  }

#pragma unroll
  for (int mf = 0; mf < 4; ++mf) {
#pragma unroll
    for (int r = 0; r < 4; ++r) {
      int slot = mblk * 128 + wm + mf * 16 + ((lane >> 4) << 2) + r;
      if (slot < c) {
        int tok = list[e * N_TOK + slot];
        float cf = coef[e * N_TOK + slot];
#pragma unroll
        for (int nf = 0; nf < 4; ++nf) {
          int col = nblk * 128 + wn + nf * 16 + (lane & 15);
          unsafeAtomicAdd(&out[(size_t)tok * D_DIM + col], cf * acc[mf][nf][r]);
        }
      }
    }
  }
}

// ------------------------------------------------------------------ launch --
extern "C" void kernel_launch(void* const* d_in, const int* in_sizes, int n_in,
                              void* d_out, int out_size, void* d_ws, size_t ws_size,
                              hipStream_t stream) {
  const float* x = (const float*)d_in[0];
  const float* gw = (const float*)d_in[1];
  const float* w1 = (const float*)d_in[2];
  const float* w2 = (const float*)d_in[3];
  float* out = (float*)d_out;
  char* ws = (char*)d_ws;

  int* cnt = (int*)(ws + CNT_OFF);
  int* hoff = (int*)(ws + HOFF_OFF);
  float* psum = (float*)(ws + PSUM_OFF);
  int* list = (int*)(ws + LIST_OFF);
  float* coef = (float*)(ws + COEF_OFF);
  unsigned short* h = (unsigned short*)(ws + H_OFF);

  // zero routing header + KL partial sums; zero output (atomic accumulation)
  hipMemsetAsync(d_ws, 0, PSUM_OFF + 2048 * 8 * 4, stream);
  hipMemsetAsync(d_out, 0, (size_t)out_size * 4, stream);

  router_kernel<<<2048, 256, 0, stream>>>(x, gw, cnt, list, coef, psum);
  prefix_kernel<<<1, 64, 0, stream>>>(cnt, hoff);
  kl_kernel<<<1, 256, 0, stream>>>(psum, out + 8388608);
  gemm1_kernel<<<dim3(32, 64, 8), 256, 0, stream>>>(x, w1, cnt, hoff, list, h);
  gemm2_kernel<<<dim3(8, 64, 8), 256, 0, stream>>>(h, w2, cnt, hoff, list, coef, out);
}

// Round 2
// 845.466 us; speedup vs baseline: 1.4926x; 1.4926x over previous
//
#include <hip/hip_runtime.h>
#include <hip/hip_bf16.h>
#include <cstdint>

// MoE top-2: B=4 S=2048 D=1024 F=4096 E=8, all fp32 in/out.
// Round 2: prep kernels convert X->bf16 and W1/W2 -> bf16 transposed, so the
// grouped GEMMs stage A/B tiles with global_load_lds width=16 (m97 structure,
// swizzled-source + linear LDS dest + swizzled reads).
//
// ws layout (full path, needs ~296 MB):
//   [0,32)       cnt[8]
//   [32,96)      hoff[9]
//   [128,256)    zpage (zeros, staging source for pad rows)
//   [256,65792)  psum[2048][8]
//   [65792,..)   list[8][8192]
//   [327936,..)  coef[8][8192]
//   [1MB)        xbf   bf16 X               16 MB
//   [18MB)       w1t   bf16 [e][f][d]       64 MB
//   [82MB)       w2t   bf16 [e][d][f]       64 MB
//   [146MB)      h     bf16 padded rows    142 MB
// Fallback (ws < FULL_WS): round-1 reg-staged kernels, h at 1MB.

#define N_TOK 8192
#define D_DIM 1024
#define F_DIM 4096
#define N_EXP 8

#define CNT_OFF   0u
#define HOFF_OFF  32u
#define ZPG_OFF   128u
#define PSUM_OFF  256u
#define LIST_OFF  65792u
#define COEF_OFF  327936u
#define H1_OFF    1048576ull          // fallback h
#define XBF_OFF   1048576ull
#define W1T_OFF   18874368ull
#define W2T_OFF   (W1T_OFF + 67108864ull)
#define H2_OFF    (W2T_OFF + 67108864ull)
#define FULL_WS   (H2_OFF + 17408ull * 4096ull * 2ull)

typedef __attribute__((ext_vector_type(8))) short short8;
typedef __attribute__((ext_vector_type(4))) float f32x4;
typedef __attribute__((ext_vector_type(4))) float float4v;
typedef __attribute__((ext_vector_type(2))) unsigned int u32x2;

__device__ __forceinline__ unsigned short f2bf(float x) {
  unsigned int u = __float_as_uint(x);
  unsigned int r = (u + 0x7fffu + ((u >> 16) & 1u)) >> 16;
  return (unsigned short)r;
}

__device__ __forceinline__ void gload16(const void* g, void* l) {
  __builtin_amdgcn_global_load_lds(
      (const __attribute__((address_space(1))) void*)g,
      (__attribute__((address_space(3))) void*)l, 16, 0, 0);
}

// ---------------------------------------------------------------- router ----
__global__ void router_kernel(const float* __restrict__ x,
                              const float* __restrict__ gw,
                              int* __restrict__ cnt, int* __restrict__ list,
                              float* __restrict__ coef,
                              float* __restrict__ psum) {
  const int wave = threadIdx.x >> 6;
  const int lane = threadIdx.x & 63;
  const int t = blockIdx.x * 4 + wave;

  __shared__ float bps[N_EXP];
  if (threadIdx.x < N_EXP) bps[threadIdx.x] = 0.f;
  __syncthreads();

  float lg[8] = {0.f, 0.f, 0.f, 0.f, 0.f, 0.f, 0.f, 0.f};
  const float* xr = x + (size_t)t * D_DIM;
#pragma unroll
  for (int i = 0; i < 16; ++i) {
    int d = lane + i * 64;
    float xv = xr[d];
    float4v w0 = *(const float4v*)(gw + d * 8);
    float4v w1 = *(const float4v*)(gw + d * 8 + 4);
    lg[0] = fmaf(xv, w0.x, lg[0]); lg[1] = fmaf(xv, w0.y, lg[1]);
    lg[2] = fmaf(xv, w0.z, lg[2]); lg[3] = fmaf(xv, w0.w, lg[3]);
    lg[4] = fmaf(xv, w1.x, lg[4]); lg[5] = fmaf(xv, w1.y, lg[5]);
    lg[6] = fmaf(xv, w1.z, lg[6]); lg[7] = fmaf(xv, w1.w, lg[7]);
  }
#pragma unroll
  for (int m = 32; m; m >>= 1) {
#pragma unroll
    for (int e = 0; e < 8; ++e) lg[e] += __shfl_xor(lg[e], m);
  }

  if (lane == 0) {
    float mx = lg[0];
#pragma unroll
    for (int e = 1; e < 8; ++e) mx = fmaxf(mx, lg[e]);
    float p[8], s = 0.f;
#pragma unroll
    for (int e = 0; e < 8; ++e) { p[e] = expf(lg[e] - mx); s += p[e]; }
    float inv = 1.f / s;
#pragma unroll
    for (int e = 0; e < 8; ++e) atomicAdd(&bps[e], p[e] * inv);

    int i0 = 0;
#pragma unroll
    for (int e = 1; e < 8; ++e) if (lg[e] > lg[i0]) i0 = e;
    int i1 = (i0 == 0) ? 1 : 0;
#pragma unroll
    for (int e = 0; e < 8; ++e) if (e != i1 && e != i0 && lg[e] > lg[i1]) i1 = e;
    float p0 = 1.f / (1.f + expf(lg[i1] - lg[i0]));
    float p1 = 1.f - p0;
    int s0 = atomicAdd(&cnt[i0], 1);
    list[i0 * N_TOK + s0] = t; coef[i0 * N_TOK + s0] = p0;
    int s1 = atomicAdd(&cnt[i1], 1);
    list[i1 * N_TOK + s1] = t; coef[i1 * N_TOK + s1] = p1;
  }
  __syncthreads();
  if (threadIdx.x < 8) psum[blockIdx.x * 8 + threadIdx.x] = bps[threadIdx.x];
}

// ---------------------------------------------------------------- prefix ----
__global__ void prefix_kernel(const int* __restrict__ cnt, int* __restrict__ hoff) {
  if (threadIdx.x == 0) {
    int o = 0;
#pragma unroll
    for (int e = 0; e < 8; ++e) {
      hoff[e] = o;
      o += ((cnt[e] + 127) >> 7) << 7;
    }
    hoff[8] = o;
  }
}

// -------------------------------------------------------------------- KL ----
__global__ void kl_kernel(const float* __restrict__ psum, float* __restrict__ out_kl) {
  __shared__ float s[8];
  if (threadIdx.x < 8) s[threadIdx.x] = 0.f;
  __syncthreads();
  float loc[8] = {0.f, 0.f, 0.f, 0.f, 0.f, 0.f, 0.f, 0.f};
  for (int r = threadIdx.x; r < 2048; r += 256) {
#pragma unroll
    for (int e = 0; e < 8; ++e) loc[e] += psum[r * 8 + e];
  }
#pragma unroll
  for (int e = 0; e < 8; ++e) atomicAdd(&s[e], loc[e]);
  __syncthreads();
  if (threadIdx.x == 0) {
    float kl = 0.f;
#pragma unroll
    for (int e = 0; e < 8; ++e) {
      float mean = s[e] / 8192.f;
      kl += (logf(0.125f) - logf(mean));
    }
    out_kl[0] = kl * (0.125f * 0.125f);
  }
}

// ------------------------------------------------------------------ prep ----
__global__ void xconv_kernel(const float* __restrict__ x,
                             unsigned short* __restrict__ xbf) {
  size_t i = ((size_t)blockIdx.x * 256 + threadIdx.x) * 8;
  float4v a = *(const float4v*)(x + i);
  float4v b = *(const float4v*)(x + i + 4);
  short8 o;
  o[0] = (short)f2bf(a.x); o[1] = (short)f2bf(a.y);
  o[2] = (short)f2bf(a.z); o[3] = (short)f2bf(a.w);
  o[4] = (short)f2bf(b.x); o[5] = (short)f2bf(b.y);
  o[6] = (short)f2bf(b.z); o[7] = (short)f2bf(b.w);
  *(short8*)(xbf + i) = o;
}

// w: [E][K][N] f32 -> wt: [E][N][K] bf16, 64x64 LDS tiles
__global__ __launch_bounds__(256) void wtrans_kernel(
    const float* __restrict__ w, unsigned short* __restrict__ wt, int K, int N) {
  const int e = blockIdx.z;
  const int n0 = blockIdx.x * 64, k0 = blockIdx.y * 64;
  __shared__ float t[64][65];
  const float* we = w + (size_t)e * K * N;
  const int nl = threadIdx.x & 63;
  const int kl4 = threadIdx.x >> 6;
#pragma unroll
  for (int r = 0; r < 16; ++r) {
    int kl = r * 4 + kl4;
    t[kl][nl] = we[(size_t)(k0 + kl) * N + n0 + nl];
  }
  __syncthreads();
  unsigned short* wte = wt + (size_t)e * K * N;
  const int kp = (threadIdx.x & 31) * 2;
  const int nl8 = threadIdx.x >> 5;
#pragma unroll
  for (int r = 0; r < 8; ++r) {
    int n = r * 8 + nl8;
    unsigned int pk = (unsigned int)f2bf(t[kp][n]) |
                      ((unsigned int)f2bf(t[kp + 1][n]) << 16);
    *(unsigned int*)(wte + (size_t)(n0 + n) * K + k0 + kp) = pk;
  }
}

// ------------------------------------------------------- MFMA frag loader ---
// LDS tiles [rows][64 bf16] (128 B rows), swizzled read: byte ^= (row&7)<<4.
__device__ __forceinline__ short8 ld_frag(const unsigned short* base, int row_base,
                                          int k_base, int lane) {
  int row = row_base + (lane & 15);
  int byte = (row * 128 + (k_base + ((lane >> 4) << 3)) * 2) ^ ((row & 7) << 4);
  return *(const short8*)((const char*)base + byte);
}

// ------------------------------------------------------------- GEMM1 (v2) ---
// h[rows,4096] = silu( Xg[rows,1024] @ W1[e] ); A = gathered xbf, B = w1t.
__global__ __launch_bounds__(256) void gemm1_v2(
    const unsigned short* __restrict__ xbf, const unsigned short* __restrict__ w1t,
    const int* __restrict__ cnt, const int* __restrict__ hoff,
    const int* __restrict__ list, const unsigned short* __restrict__ zpage,
    unsigned short* __restrict__ h) {
  const int e = blockIdx.z, mblk = blockIdx.y, nblk = blockIdx.x;
  const int c = cnt[e];
  if (mblk * 128 >= c) return;
  const int tid = threadIdx.x, lane = tid & 63, wave = tid >> 6;
  const int wm = (wave >> 1) * 64, wn = (wave & 1) * 64;

  __shared__ unsigned short At[128 * 64];
  __shared__ unsigned short Bt[128 * 64];

  // staging sources: thread covers LDS bytes {i*4096 + tid*16} for i=0..3
  // row = i*32 + (tid>>3); src within-row byte = (tid*16 &127) ^ ((row&7)<<4)
  const int wb = (tid * 16) & 127;
  const int rowb = tid >> 3;            // row base (i adds 32, row&7 invariant)
  const int sw = wb ^ ((rowb & 7) << 4);
  const char* asrc[4]; int astep[4];
  const char* bsrc[4];
#pragma unroll
  for (int i = 0; i < 4; ++i) {
    int row = i * 32 + rowb;
    int slot = mblk * 128 + row;
    if (slot < c) {
      int tok = list[e * N_TOK + slot];
      asrc[i] = (const char*)(xbf + (size_t)tok * D_DIM) + sw;
      astep[i] = 128;
    } else {
      asrc[i] = (const char*)zpage + sw;
      astep[i] = 0;
    }
    bsrc[i] = (const char*)(w1t + ((size_t)e * F_DIM + nblk * 128 + row) * D_DIM) + sw;
  }

  f32x4 acc[4][4];
#pragma unroll
  for (int i = 0; i < 4; ++i)
#pragma unroll
    for (int j = 0; j < 4; ++j) acc[i][j] = f32x4{0.f, 0.f, 0.f, 0.f};

  char* ldsA = (char*)At;
  char* ldsB = (char*)Bt;
  for (int kc = 0; kc < 16; ++kc) {
    __syncthreads();
#pragma unroll
    for (int i = 0; i < 4; ++i) {
      gload16(asrc[i], ldsA + i * 4096 + wave * 1024);
      gload16(bsrc[i], ldsB + i * 4096 + wave * 1024);
      asrc[i] += astep[i];
      bsrc[i] += 128;
    }
    __syncthreads();
#pragma unroll
    for (int ks = 0; ks < 2; ++ks) {
      short8 af[4], bb[4];
#pragma unroll
      for (int mf = 0; mf < 4; ++mf) af[mf] = ld_frag(At, wm + mf * 16, ks * 32, lane);
#pragma unroll
      for (int nf = 0; nf < 4; ++nf) bb[nf] = ld_frag(Bt, wn + nf * 16, ks * 32, lane);
#pragma unroll
      for (int mf = 0; mf < 4; ++mf)
#pragma unroll
        for (int nf = 0; nf < 4; ++nf)
          acc[mf][nf] = __builtin_amdgcn_mfma_f32_16x16x32_bf16(
              af[mf], bb[nf], acc[mf][nf], 0, 0, 0);
    }
  }

  const int hbase = hoff[e] + mblk * 128;
#pragma unroll
  for (int mf = 0; mf < 4; ++mf)
#pragma unroll
    for (int nf = 0; nf < 4; ++nf)
#pragma unroll
      for (int r = 0; r < 4; ++r) {
        float v = acc[mf][nf][r];
        v = v / (1.f + __expf(-v));
        int row = wm + mf * 16 + ((lane >> 4) << 2) + r;
        int col = nblk * 128 + wn + nf * 16 + (lane & 15);
        h[(size_t)(hbase + row) * F_DIM + col] = f2bf(v);
      }
}

// ------------------------------------------------------------- GEMM2 (v2) ---
// out[tok,:] += coef * ( h[rows,4096] @ W2[e] ); A = h bf16, B = w2t.
__global__ __launch_bounds__(256) void gemm2_v2(
    const unsigned short* __restrict__ h, const unsigned short* __restrict__ w2t,
    const int* __restrict__ cnt, const int* __restrict__ hoff,
    const int* __restrict__ list, const float* __restrict__ coef,
    float* __restrict__ out) {
  const int e = blockIdx.z, mblk = blockIdx.y, nblk = blockIdx.x;
  const int c = cnt[e];
  if (mblk * 128 >= c) return;
  const int tid = threadIdx.x, lane = tid & 63, wave = tid >> 6;
  const int wm = (wave >> 1) * 64, wn = (wave & 1) * 64;

  __shared__ unsigned short At[128 * 64];
  __shared__ unsigned short Bt[128 * 64];

  const int wb = (tid * 16) & 127;
  const int rowb = tid >> 3;
  const int sw = wb ^ ((rowb & 7) << 4);
  const int hbase = hoff[e] + mblk * 128;
  const char* asrc[4];
  const char* bsrc[4];
#pragma unroll
  for (int i = 0; i < 4; ++i) {
    int row = i * 32 + rowb;
    asrc[i] = (const char*)(h + (size_t)(hbase + row) * F_DIM) + sw;
    bsrc[i] = (const char*)(w2t + ((size_t)e * D_DIM + nblk * 128 + row) * F_DIM) + sw;
  }

  f32x4 acc[4][4];
#pragma unroll
  for (int i = 0; i < 4; ++i)
#pragma unroll
    for (int j = 0; j < 4; ++j) acc[i][j] = f32x4{0.f, 0.f, 0.f, 0.f};

  char* ldsA = (char*)At;
  char* ldsB = (char*)Bt;
  for (int kc = 0; kc < 64; ++kc) {
    __syncthreads();
#pragma unroll
    for (int i = 0; i < 4; ++i) {
      gload16(asrc[i], ldsA + i * 4096 + wave * 1024);
      gload16(bsrc[i], ldsB + i * 4096 + wave * 1024);
      asrc[i] += 128;
      bsrc[i] += 128;
    }
    __syncthreads();
#pragma unroll
    for (int ks = 0; ks < 2; ++ks) {
      short8 af[4], bb[4];
#pragma unroll
      for (int mf = 0; mf < 4; ++mf) af[mf] = ld_frag(At, wm + mf * 16, ks * 32, lane);
#pragma unroll
      for (int nf = 0; nf < 4; ++nf) bb[nf] = ld_frag(Bt, wn + nf * 16, ks * 32, lane);
#pragma unroll
      for (int mf = 0; mf < 4; ++mf)
#pragma unroll
        for (int nf = 0; nf < 4; ++nf)
          acc[mf][nf] = __builtin_amdgcn_mfma_f32_16x16x32_bf16(
              af[mf], bb[nf], acc[mf][nf], 0, 0, 0);
    }
  }

#pragma unroll
  for (int mf = 0; mf < 4; ++mf) {
#pragma unroll
    for (int r = 0; r < 4; ++r) {
      int slot = mblk * 128 + wm + mf * 16 + ((lane >> 4) << 2) + r;
      if (slot < c) {
        int tok = list[e * N_TOK + slot];
        float cf = coef[e * N_TOK + slot];
#pragma unroll
        for (int nf = 0; nf < 4; ++nf) {
          int col = nblk * 128 + wn + nf * 16 + (lane & 15);
          unsafeAtomicAdd(&out[(size_t)tok * D_DIM + col], cf * acc[mf][nf][r]);
        }
      }
    }
  }
}

// ------------------------------------------------- fallback (round-1) GEMMs --
__global__ __launch_bounds__(256) void gemm1_v1(
    const float* __restrict__ x, const float* __restrict__ w1,
    const int* __restrict__ cnt, const int* __restrict__ hoff,
    const int* __restrict__ list, unsigned short* __restrict__ h) {
  const int e = blockIdx.z, mblk = blockIdx.y, nblk = blockIdx.x;
  const int c = cnt[e];
  if (mblk * 128 >= c) return;
  const int tid = threadIdx.x, lane = tid & 63, wave = tid >> 6;
  const int wm = (wave >> 1) * 64, wn = (wave & 1) * 64;

  __shared__ unsigned short At[128 * 64];
  __shared__ unsigned short Bt[128 * 64];
  __shared__ int toks[128];
  if (tid < 128) {
    int slot = mblk * 128 + tid;
    toks[tid] = (slot < c) ? list[e * N_TOK + slot] : -1;
  }
  __syncthreads();

  f32x4 acc[4][4];
#pragma unroll
  for (int i = 0; i < 4; ++i)
#pragma unroll
    for (int j = 0; j < 4; ++j) acc[i][j] = f32x4{0.f, 0.f, 0.f, 0.f};

  const float* w1e = w1 + (size_t)e * D_DIM * F_DIM;
  for (int kc = 0; kc < 16; ++kc) {
    __syncthreads();
#pragma unroll
    for (int it = 0; it < 8; ++it) {
      int lin = it * 256 + tid;
      int row = lin >> 4, c4 = lin & 15;
      int tok = toks[row];
      unsigned int lo = 0u, hi = 0u;
      if (tok >= 0) {
        float4v f = *(const float4v*)(x + (size_t)tok * D_DIM + kc * 64 + c4 * 4);
        lo = (unsigned int)f2bf(f.x) | ((unsigned int)f2bf(f.y) << 16);
        hi = (unsigned int)f2bf(f.z) | ((unsigned int)f2bf(f.w) << 16);
      }
      int byte = (row * 128 + c4 * 8) ^ ((row & 7) << 4);
      *(u32x2*)((char*)At + byte) = u32x2{lo, hi};
    }
#pragma unroll
    for (int it = 0; it < 16; ++it) {
      int lin = it * 256 + tid;
      int f_loc = lin & 127, dp = lin >> 7;
      int d = kc * 64 + dp * 2;
      const float* src = w1e + (size_t)d * F_DIM + nblk * 128 + f_loc;
      unsigned int pk = (unsigned int)f2bf(src[0]) |
                        ((unsigned int)f2bf(src[F_DIM]) << 16);
      int byte = (f_loc * 128 + dp * 4) ^ ((f_loc & 7) << 4);
      *(unsigned int*)((char*)Bt + byte) = pk;
    }
    __syncthreads();
#pragma unroll
    for (int ks = 0; ks < 2; ++ks) {
      short8 af[4], bb[4];
#pragma unroll
      for (int mf = 0; mf < 4; ++mf) af[mf] = ld_frag(At, wm + mf * 16, ks * 32, lane);
#pragma unroll
      for (int nf = 0; nf < 4; ++nf) bb[nf] = ld_frag(Bt, wn + nf * 16, ks * 32, lane);
#pragma unroll
      for (int mf = 0; mf < 4; ++mf)
#pragma unroll
        for (int nf = 0; nf < 4; ++nf)
          acc[mf][nf] = __builtin_amdgcn_mfma_f32_16x16x32_bf16(
              af[mf], bb[nf], acc[mf][nf], 0, 0, 0);
    }
  }

  const int hbase = hoff[e] + mblk * 128;
#pragma unroll
  for (int mf = 0; mf < 4; ++mf)
#pragma unroll
    for (int nf = 0; nf < 4; ++nf)
#pragma unroll
      for (int r = 0; r < 4; ++r) {
        float v = acc[mf][nf][r];
        v = v / (1.f + __expf(-v));
        int row = wm + mf * 16 + ((lane >> 4) << 2) + r;
        int col = nblk * 128 + wn + nf * 16 + (lane & 15);
        h[(size_t)(hbase + row) * F_DIM + col] = f2bf(v);
      }
}

__global__ __launch_bounds__(256) void gemm2_v1(
    const unsigned short* __restrict__ h, const float* __restrict__ w2,
    const int* __restrict__ cnt, const int* __restrict__ hoff,
    const int* __restrict__ list, const float* __restrict__ coef,
    float* __restrict__ out) {
  const int e = blockIdx.z, mblk = blockIdx.y, nblk = blockIdx.x;
  const int c = cnt[e];
  if (mblk * 128 >= c) return;
  const int tid = threadIdx.x, lane = tid & 63, wave = tid >> 6;
  const int wm = (wave >> 1) * 64, wn = (wave & 1) * 64;

  __shared__ unsigned short At[128 * 64];
  __shared__ unsigned short Bt[128 * 64];

  f32x4 acc[4][4];
#pragma unroll
  for (int i = 0; i < 4; ++i)
#pragma unroll
    for (int j = 0; j < 4; ++j) acc[i][j] = f32x4{0.f, 0.f, 0.f, 0.f};

  const int hbase = hoff[e] + mblk * 128;
  const float* w2e = w2 + (size_t)e * F_DIM * D_DIM;
  for (int kc = 0; kc < 64; ++kc) {
    __syncthreads();
#pragma unroll
    for (int it = 0; it < 8; ++it) {
      int lin = it * 256 + tid;
      int row = lin >> 4, c4 = lin & 15;
      u32x2 v = *(const u32x2*)(h + (size_t)(hbase + row) * F_DIM + kc * 64 + c4 * 4);
      int byte = (row * 128 + c4 * 8) ^ ((row & 7) << 4);
      *(u32x2*)((char*)At + byte) = v;
    }
#pragma unroll
    for (int it = 0; it < 16; ++it) {
      int lin = it * 256 + tid;
      int dcol = lin & 127, kp = lin >> 7;
      int k = kc * 64 + kp * 2;
      const float* src = w2e + (size_t)k * D_DIM + nblk * 128 + dcol;
      unsigned int pk = (unsigned int)f2bf(src[0]) |
                        ((unsigned int)f2bf(src[D_DIM]) << 16);
      int byte = (dcol * 128 + kp * 4) ^ ((dcol & 7) << 4);
      *(unsigned int*)((char*)Bt + byte) = pk;
    }
    __syncthreads();
#pragma unroll
    for (int ks = 0; ks < 2; ++ks) {
      short8 af[4], bb[4];
#pragma unroll
      for (int mf = 0; mf < 4; ++mf) af[mf] = ld_frag(At, wm + mf * 16, ks * 32, lane);
#pragma unroll
      for (int nf = 0; nf < 4; ++nf) bb[nf] = ld_frag(Bt, wn + nf * 16, ks * 32, lane);
#pragma unroll
      for (int mf = 0; mf < 4; ++mf)
#pragma unroll
        for (int nf = 0; nf < 4; ++nf)
          acc[mf][nf] = __builtin_amdgcn_mfma_f32_16x16x32_bf16(
              af[mf], bb[nf], acc[mf][nf], 0, 0, 0);
    }
  }

#pragma unroll
  for (int mf = 0; mf < 4; ++mf) {
#pragma unroll
    for (int r = 0; r < 4; ++r) {
      int slot = mblk * 128 + wm + mf * 16 + ((lane >> 4) << 2) + r;
      if (slot < c) {
        int tok = list[e * N_TOK + slot];
        float cf = coef[e * N_TOK + slot];
#pragma unroll
        for (int nf = 0; nf < 4; ++nf) {
          int col = nblk * 128 + wn + nf * 16 + (lane & 15);
          unsafeAtomicAdd(&out[(size_t)tok * D_DIM + col], cf * acc[mf][nf][r]);
        }
      }
    }
  }
}

// ------------------------------------------------------------------ launch --
extern "C" void kernel_launch(void* const* d_in, const int* in_sizes, int n_in,
                              void* d_out, int out_size, void* d_ws, size_t ws_size,
                              hipStream_t stream) {
  const float* x = (const float*)d_in[0];
  const float* gw = (const float*)d_in[1];
  const float* w1 = (const float*)d_in[2];
  const float* w2 = (const float*)d_in[3];
  float* out = (float*)d_out;
  char* ws = (char*)d_ws;

  int* cnt = (int*)(ws + CNT_OFF);
  int* hoff = (int*)(ws + HOFF_OFF);
  float* psum = (float*)(ws + PSUM_OFF);
  int* list = (int*)(ws + LIST_OFF);
  float* coef = (float*)(ws + COEF_OFF);

  hipMemsetAsync(d_ws, 0, PSUM_OFF + 2048 * 8 * 4, stream);
  hipMemsetAsync(d_out, 0, (size_t)out_size * 4, stream);

  router_kernel<<<2048, 256, 0, stream>>>(x, gw, cnt, list, coef, psum);
  prefix_kernel<<<1, 64, 0, stream>>>(cnt, hoff);
  kl_kernel<<<1, 256, 0, stream>>>(psum, out + 8388608);

  if (ws_size >= FULL_WS) {
    unsigned short* xbf = (unsigned short*)(ws + XBF_OFF);
    unsigned short* w1t = (unsigned short*)(ws + W1T_OFF);
    unsigned short* w2t = (unsigned short*)(ws + W2T_OFF);
    unsigned short* h = (unsigned short*)(ws + H2_OFF);
    const unsigned short* zpage = (const unsigned short*)(ws + ZPG_OFF);

    xconv_kernel<<<4096, 256, 0, stream>>>(x, xbf);
    wtrans_kernel<<<dim3(64, 16, 8), 256, 0, stream>>>(w1, w1t, 1024, 4096);
    wtrans_kernel<<<dim3(16, 64, 8), 256, 0, stream>>>(w2, w2t, 4096, 1024);
    gemm1_v2<<<dim3(32, 64, 8), 256, 0, stream>>>(xbf, w1t, cnt, hoff, list, zpage, h);
    gemm2_v2<<<dim3(8, 64, 8), 256, 0, stream>>>(h, w2t, cnt, hoff, list, coef, out);
  } else {
    unsigned short* h = (unsigned short*)(ws + H1_OFF);
    gemm1_v1<<<dim3(32, 64, 8), 256, 0, stream>>>(x, w1, cnt, hoff, list, h);
    gemm2_v1<<<dim3(8, 64, 8), 256, 0, stream>>>(h, w2, cnt, hoff, list, coef, out);
  }
}